// Round 1
// baseline (372.925 us; speedup 1.0000x reference)
//
#include <hip/hip_runtime.h>
#include <math.h>

#define BB 4
#define CC 64
#define OO 64
#define HH 128
#define WW 128
#define K2 9
#define HWsz (HH * WW)

// ---------------------------------------------------------------------------
// Kernel 1: fused offset+mask 3x3 conv. One thread per output pixel (b,h,w),
// computes all 27 channels. Weights are wave-uniform -> scalar loads.
// ---------------------------------------------------------------------------
__global__ __launch_bounds__(256) void convom_kernel(
    const float* __restrict__ x, const float* __restrict__ ow,
    const float* __restrict__ ob, const float* __restrict__ mw,
    const float* __restrict__ mb, float* __restrict__ offs,
    float* __restrict__ mask)
{
    int pid = blockIdx.x * blockDim.x + threadIdx.x;   // 0 .. B*HW-1
    int b = pid / HWsz;
    int p = pid % HWsz;
    int h = p / WW;
    int w = p % WW;

    float accO[18];
    float accM[9];
#pragma unroll
    for (int i = 0; i < 18; ++i) accO[i] = ob[i];
#pragma unroll
    for (int i = 0; i < 9; ++i) accM[i] = mb[i];

    const float* xb = x + b * CC * HWsz;
    for (int c = 0; c < CC; ++c) {
        float v[9];
#pragma unroll
        for (int ky = 0; ky < 3; ++ky) {
            int yy = h + ky - 1;
#pragma unroll
            for (int kx = 0; kx < 3; ++kx) {
                int xx = w + kx - 1;
                bool in = (yy >= 0) & (yy < HH) & (xx >= 0) & (xx < WW);
                v[ky * 3 + kx] = in ? xb[c * HWsz + yy * WW + xx] : 0.0f;
            }
        }
        const float* owc = ow + c * 9;   // ow[co*576 + c*9 + kk]
#pragma unroll
        for (int co = 0; co < 18; ++co) {
#pragma unroll
            for (int kk = 0; kk < 9; ++kk)
                accO[co] += owc[co * 576 + kk] * v[kk];
        }
        const float* mwc = mw + c * 9;
#pragma unroll
        for (int co = 0; co < 9; ++co) {
#pragma unroll
            for (int kk = 0; kk < 9; ++kk)
                accM[co] += mwc[co * 576 + kk] * v[kk];
        }
    }
#pragma unroll
    for (int i = 0; i < 18; ++i)
        offs[(b * 18 + i) * HWsz + p] = accO[i];
#pragma unroll
    for (int i = 0; i < 9; ++i)
        mask[(b * 9 + i) * HWsz + p] = 1.0f / (1.0f + expf(-accM[i]));
}

// ---------------------------------------------------------------------------
// Kernel 2: weight transpose -> wT[(c*9+k)*64 + o] = weight[o*576 + c*9 + k]
// so the inner o-loop in the deform kernel reads 64 contiguous floats.
// ---------------------------------------------------------------------------
__global__ __launch_bounds__(256) void wtrans_kernel(
    const float* __restrict__ wgt, float* __restrict__ wT)
{
    int i = blockIdx.x * blockDim.x + threadIdx.x;  // 0 .. 36863
    int o = i % 64;          // fast dim -> coalesced write
    int ck = i / 64;         // c*9+k
    wT[ck * 64 + o] = wgt[o * 576 + ck];
}

// ---------------------------------------------------------------------------
// Kernel 3: deformable sampling + main contraction. One thread per pixel,
// acc[64] output channels. Bilinear semantics match the reference exactly:
// clip indices for the gather, zero the weight of out-of-bounds corners.
// ---------------------------------------------------------------------------
__global__ __launch_bounds__(256) void deform_kernel(
    const float* __restrict__ x, const float* __restrict__ offs,
    const float* __restrict__ mask, const float* __restrict__ wT,
    float* __restrict__ out)
{
    int pid = blockIdx.x * blockDim.x + threadIdx.x;
    int b = pid / HWsz;
    int p = pid % HWsz;
    int h = p / WW;
    int w = p % WW;

    float acc[OO];
#pragma unroll
    for (int o = 0; o < OO; ++o) acc[o] = 0.0f;

    const float* xb = x + b * CC * HWsz;

    for (int k = 0; k < K2; ++k) {
        int ky = k / 3, kx = k % 3;
        float oy = offs[(b * 18 + 2 * k) * HWsz + p];
        float ox = offs[(b * 18 + 2 * k + 1) * HWsz + p];
        float mk = mask[(b * 9 + k) * HWsz + p];

        float py = oy + (float)(h - 1 + ky);
        float px = ox + (float)(w - 1 + kx);
        float y0f = floorf(py), x0f = floorf(px);
        float dy = py - y0f, dx = px - x0f;
        int y0 = (int)y0f, x0 = (int)x0f;
        int y1 = y0 + 1, x1 = x0 + 1;

        bool vy0 = (y0 >= 0) & (y0 < HH);
        bool vy1 = (y1 >= 0) & (y1 < HH);
        bool vx0 = (x0 >= 0) & (x0 < WW);
        bool vx1 = (x1 >= 0) & (x1 < WW);
        float w00 = (vy0 & vx0) ? (1.0f - dy) * (1.0f - dx) : 0.0f;
        float w01 = (vy0 & vx1) ? (1.0f - dy) * dx : 0.0f;
        float w10 = (vy1 & vx0) ? dy * (1.0f - dx) : 0.0f;
        float w11 = (vy1 & vx1) ? dy * dx : 0.0f;

        int yc0 = min(max(y0, 0), HH - 1);
        int yc1 = min(max(y1, 0), HH - 1);
        int xc0 = min(max(x0, 0), WW - 1);
        int xc1 = min(max(x1, 0), WW - 1);
        int i00 = yc0 * WW + xc0;
        int i01 = yc0 * WW + xc1;
        int i10 = yc1 * WW + xc0;
        int i11 = yc1 * WW + xc1;

        const float* wk = wT + k * 64;   // + c*576 later
        for (int c = 0; c < CC; ++c) {
            const float* xc = xb + c * HWsz;
            float s = w00 * xc[i00] + w01 * xc[i01]
                    + w10 * xc[i10] + w11 * xc[i11];
            s *= mk;
            const float* wrow = wk + c * 9 * 64;   // wT[(c*9+k)*64 + o]
#pragma unroll
            for (int o = 0; o < OO; ++o)
                acc[o] += s * wrow[o];
        }
    }

    float* outb = out + b * OO * HWsz + p;
#pragma unroll
    for (int o = 0; o < OO; ++o)
        outb[o * HWsz] = acc[o];
}

extern "C" void kernel_launch(void* const* d_in, const int* in_sizes, int n_in,
                              void* d_out, int out_size, void* d_ws, size_t ws_size,
                              hipStream_t stream)
{
    const float* x   = (const float*)d_in[0];
    const float* ow  = (const float*)d_in[1];
    const float* ob  = (const float*)d_in[2];
    const float* mw  = (const float*)d_in[3];
    const float* mb  = (const float*)d_in[4];
    const float* wgt = (const float*)d_in[5];
    float* out = (float*)d_out;

    // Workspace layout (floats):
    //   offs: B*18*HW = 1,179,648
    //   mask: B*9*HW  =   589,824
    //   wT:   576*64  =    36,864
    float* offs = (float*)d_ws;
    float* mask = offs + (size_t)BB * 18 * HWsz;
    float* wT   = mask + (size_t)BB * 9 * HWsz;

    wtrans_kernel<<<dim3(144), dim3(256), 0, stream>>>(wgt, wT);
    convom_kernel<<<dim3((BB * HWsz) / 256), dim3(256), 0, stream>>>(
        x, ow, ob, mw, mb, offs, mask);
    deform_kernel<<<dim3((BB * HWsz) / 256), dim3(256), 0, stream>>>(
        x, offs, mask, wT, out);
}

// Round 2
// 204.742 us; speedup vs baseline: 1.8214x; 1.8214x over previous
//
#include <hip/hip_runtime.h>
#include <math.h>

#define BB 4
#define CC 64
#define OO 64
#define HH 128
#define WW 128
#define HWsz (HH * WW)

typedef __attribute__((ext_vector_type(8))) short short8;
typedef __attribute__((ext_vector_type(4))) short short4v;
typedef __attribute__((ext_vector_type(4))) float floatx4;

// fp32 -> bf16 with round-to-nearest-even
static __device__ __forceinline__ short f2bf(float f) {
    union { float f; unsigned u; } v; v.f = f;
    unsigned r = (v.u + 0x7fffu + ((v.u >> 16) & 1u)) >> 16;
    return (short)r;
}

// XOR-swizzled LDS index (shorts) for Bt[px][c], px in [0,128), c in [0,64).
// 8B-granule swizzle: slot8 = c/4, slot8' = slot8 ^ (px & 15).
static __device__ __forceinline__ int bt_idx(int px, int c) {
    return px * 64 + ((((c >> 2) ^ (px & 15)) << 2) | (c & 3));
}

// ---------------------------------------------------------------------------
// prep: bf16 weight repack with K reordered as [k][c] (k = tap index).
//   wbfT[o*576 + k*64 + c] = bf16(weight[o][c][k])          (64 rows)
//   womT[o*576 + k*64 + c] = bf16(offset/mask conv weights) (32 rows, 27 used)
// ---------------------------------------------------------------------------
__global__ __launch_bounds__(256) void prep_kernel(
    const float* __restrict__ wgt, const float* __restrict__ ow,
    const float* __restrict__ mw, short* __restrict__ wbfT,
    short* __restrict__ womT)
{
    int i = blockIdx.x * 256 + threadIdx.x;
    if (i < 64 * 576) {
        int o = i / 576, r = i % 576;
        int k = r >> 6, c = r & 63;
        wbfT[i] = f2bf(wgt[o * 576 + c * 9 + k]);
    } else if (i < 64 * 576 + 32 * 576) {
        int j = i - 64 * 576;
        int o = j / 576, r = j % 576;
        int k = r >> 6, c = r & 63;
        float v = 0.0f;
        if (o < 18) v = ow[o * 576 + c * 9 + k];
        else if (o < 27) v = mw[(o - 18) * 576 + c * 9 + k];
        womT[j] = f2bf(v);
    }
}

// ---------------------------------------------------------------------------
// convgemm: offset+mask conv as implicit-im2col MFMA GEMM.
// Block = (row h, batch b): out tile M=32(ch) x N=128(px), K=576 as 9 taps x 64c.
// ---------------------------------------------------------------------------
__global__ __launch_bounds__(256) void convgemm_kernel(
    const float* __restrict__ x, const short* __restrict__ womT,
    const float* __restrict__ ob, const float* __restrict__ mb,
    float* __restrict__ offs, float* __restrict__ mask)
{
    __shared__ __align__(16) short Bt[128 * 64];
    int tid = threadIdx.x;
    int b = blockIdx.y;
    int h = blockIdx.x;
    int p0 = h * WW;
    int pxl = tid & 127;
    int eg = tid >> 7;
    int lane = tid & 63;
    int wv = tid >> 6;

    const float* xb = x + (size_t)b * CC * HWsz;

    floatx4 acc[2][2];
#pragma unroll
    for (int m = 0; m < 2; ++m)
#pragma unroll
        for (int n = 0; n < 2; ++n) acc[m][n] = (floatx4){0.f, 0.f, 0.f, 0.f};

#pragma unroll 1
    for (int k = 0; k < 9; ++k) {
        int ky = k / 3, kx = k % 3;
        int yy = h + ky - 1;
        int xx = pxl + kx - 1;
        bool valid = (yy >= 0) & (yy < HH) & (xx >= 0) & (xx < WW);
        int base = yy * WW + xx;

        __syncthreads();
#pragma unroll
        for (int e4 = 0; e4 < 8; ++e4) {
            short4v pk;
#pragma unroll
            for (int q = 0; q < 4; ++q) {
                int c = eg * 32 + e4 * 4 + q;
                float v = valid ? xb[c * HWsz + base] : 0.0f;
                pk[q] = f2bf(v);
            }
            *(short4v*)&Bt[bt_idx(pxl, eg * 32 + e4 * 4)] = pk;
        }
        __syncthreads();

#pragma unroll
        for (int kh = 0; kh < 2; ++kh) {
            short8 bfrag[2];
#pragma unroll
            for (int n = 0; n < 2; ++n) {
                int px = wv * 32 + n * 16 + (lane & 15);
                int cb = kh * 32 + (lane >> 4) * 8;
                short4v lo = *(short4v*)&Bt[bt_idx(px, cb)];
                short4v hi = *(short4v*)&Bt[bt_idx(px, cb + 4)];
                short8 f;
                f[0] = lo[0]; f[1] = lo[1]; f[2] = lo[2]; f[3] = lo[3];
                f[4] = hi[0]; f[5] = hi[1]; f[6] = hi[2]; f[7] = hi[3];
                bfrag[n] = f;
            }
#pragma unroll
            for (int m = 0; m < 2; ++m) {
                int o = m * 16 + (lane & 15);
                short8 afrag = *(const short8*)&womT[o * 576 + k * 64 + kh * 32 + (lane >> 4) * 8];
#pragma unroll
                for (int n = 0; n < 2; ++n)
                    acc[m][n] = __builtin_amdgcn_mfma_f32_16x16x32_bf16(
                        afrag, bfrag[n], acc[m][n], 0, 0, 0);
            }
        }
    }

    // epilogue: rows 0..17 -> offs (+bias), 18..26 -> mask (sigmoid), 27..31 drop
#pragma unroll
    for (int m = 0; m < 2; ++m)
#pragma unroll
        for (int n = 0; n < 2; ++n)
#pragma unroll
            for (int j = 0; j < 4; ++j) {
                int o = m * 16 + (lane >> 4) * 4 + j;
                int px = p0 + wv * 32 + n * 16 + (lane & 15);
                float v = acc[m][n][j];
                if (o < 18) {
                    offs[((size_t)b * 18 + o) * HWsz + px] = v + ob[o];
                } else if (o < 27) {
                    float s = v + mb[o - 18];
                    mask[((size_t)b * 9 + (o - 18)) * HWsz + px] =
                        1.0f / (1.0f + expf(-s));
                }
            }
}

// ---------------------------------------------------------------------------
// deformgemm: bilinear sampling (params in registers, mask folded into
// weights) -> bf16 samples in swizzled LDS -> MFMA contraction.
// Block = (row h, batch b): out tile M=64(o) x N=128(px), K = 9 taps x 64c.
// ---------------------------------------------------------------------------
__global__ __launch_bounds__(256) void deformgemm_kernel(
    const float* __restrict__ x, const short* __restrict__ wbfT,
    const float* __restrict__ offs, const float* __restrict__ mask,
    float* __restrict__ out)
{
    __shared__ __align__(16) short Bt[128 * 64];
    int tid = threadIdx.x;
    int b = blockIdx.y;
    int h = blockIdx.x;
    int p0 = h * WW;
    int pxl = tid & 127;
    int eg = tid >> 7;
    int lane = tid & 63;
    int wv = tid >> 6;

    const float* xb = x + (size_t)b * CC * HWsz;

    floatx4 acc[4][2];
#pragma unroll
    for (int m = 0; m < 4; ++m)
#pragma unroll
        for (int n = 0; n < 2; ++n) acc[m][n] = (floatx4){0.f, 0.f, 0.f, 0.f};

#pragma unroll 1
    for (int k = 0; k < 9; ++k) {
        int ky = k / 3, kx = k % 3;
        int p = p0 + pxl;
        float oy = offs[((size_t)b * 18 + 2 * k) * HWsz + p];
        float ox = offs[((size_t)b * 18 + 2 * k + 1) * HWsz + p];
        float mk = mask[((size_t)b * 9 + k) * HWsz + p];

        float py = oy + (float)(h + ky - 1);
        float pxf = ox + (float)(pxl + kx - 1);
        float y0f = floorf(py), x0f = floorf(pxf);
        float dy = py - y0f, dx = pxf - x0f;
        int y0 = (int)y0f, x0 = (int)x0f;
        int y1 = y0 + 1, x1 = x0 + 1;

        bool vy0 = (y0 >= 0) & (y0 < HH);
        bool vy1 = (y1 >= 0) & (y1 < HH);
        bool vx0 = (x0 >= 0) & (x0 < WW);
        bool vx1 = (x1 >= 0) & (x1 < WW);
        float w00 = (vy0 & vx0) ? (1.0f - dy) * (1.0f - dx) * mk : 0.0f;
        float w01 = (vy0 & vx1) ? (1.0f - dy) * dx * mk : 0.0f;
        float w10 = (vy1 & vx0) ? dy * (1.0f - dx) * mk : 0.0f;
        float w11 = (vy1 & vx1) ? dy * dx * mk : 0.0f;

        int yc0 = min(max(y0, 0), HH - 1);
        int yc1 = min(max(y1, 0), HH - 1);
        int xc0 = min(max(x0, 0), WW - 1);
        int xc1 = min(max(x1, 0), WW - 1);
        int i00 = yc0 * WW + xc0;
        int i01 = yc0 * WW + xc1;
        int i10 = yc1 * WW + xc0;
        int i11 = yc1 * WW + xc1;

        __syncthreads();
#pragma unroll
        for (int e4 = 0; e4 < 8; ++e4) {
            short4v pk;
#pragma unroll
            for (int q = 0; q < 4; ++q) {
                int c = eg * 32 + e4 * 4 + q;
                int cb = c * HWsz;
                float g00 = xb[cb + i00];
                float g01 = xb[cb + i01];
                float g10 = xb[cb + i10];
                float g11 = xb[cb + i11];
                float s = w00 * g00 + w01 * g01 + w10 * g10 + w11 * g11;
                pk[q] = f2bf(s);
            }
            *(short4v*)&Bt[bt_idx(pxl, eg * 32 + e4 * 4)] = pk;
        }
        __syncthreads();

#pragma unroll
        for (int kh = 0; kh < 2; ++kh) {
            short8 bfrag[2];
#pragma unroll
            for (int n = 0; n < 2; ++n) {
                int px = wv * 32 + n * 16 + (lane & 15);
                int cb = kh * 32 + (lane >> 4) * 8;
                short4v lo = *(short4v*)&Bt[bt_idx(px, cb)];
                short4v hi = *(short4v*)&Bt[bt_idx(px, cb + 4)];
                short8 f;
                f[0] = lo[0]; f[1] = lo[1]; f[2] = lo[2]; f[3] = lo[3];
                f[4] = hi[0]; f[5] = hi[1]; f[6] = hi[2]; f[7] = hi[3];
                bfrag[n] = f;
            }
#pragma unroll
            for (int m = 0; m < 4; ++m) {
                int o = m * 16 + (lane & 15);
                short8 afrag = *(const short8*)&wbfT[o * 576 + k * 64 + kh * 32 + (lane >> 4) * 8];
#pragma unroll
                for (int n = 0; n < 2; ++n)
                    acc[m][n] = __builtin_amdgcn_mfma_f32_16x16x32_bf16(
                        afrag, bfrag[n], acc[m][n], 0, 0, 0);
            }
        }
    }

    // epilogue: D row = o = m*16 + (lane>>4)*4 + j, col = px
#pragma unroll
    for (int m = 0; m < 4; ++m)
#pragma unroll
        for (int n = 0; n < 2; ++n)
#pragma unroll
            for (int j = 0; j < 4; ++j) {
                int o = m * 16 + (lane >> 4) * 4 + j;
                int px = p0 + wv * 32 + n * 16 + (lane & 15);
                out[((size_t)b * OO + o) * HWsz + px] = acc[m][n][j];
            }
}

extern "C" void kernel_launch(void* const* d_in, const int* in_sizes, int n_in,
                              void* d_out, int out_size, void* d_ws, size_t ws_size,
                              hipStream_t stream)
{
    const float* x   = (const float*)d_in[0];
    const float* ow  = (const float*)d_in[1];
    const float* ob  = (const float*)d_in[2];
    const float* mw  = (const float*)d_in[3];
    const float* mb  = (const float*)d_in[4];
    const float* wgt = (const float*)d_in[5];
    float* out = (float*)d_out;

    // ws layout: offs (4*18*HW f32) | mask (4*9*HW f32) | wbfT (64*576 bf16)
    //            | womT (32*576 bf16)   -- total ~7.2 MB
    float* offs = (float*)d_ws;
    float* mask = offs + (size_t)BB * 18 * HWsz;
    short* wbfT = (short*)(mask + (size_t)BB * 9 * HWsz);
    short* womT = wbfT + 64 * 576;

    prep_kernel<<<dim3((64 * 576 + 32 * 576 + 255) / 256), dim3(256), 0, stream>>>(
        wgt, ow, mw, wbfT, womT);
    convgemm_kernel<<<dim3(HH, BB), dim3(256), 0, stream>>>(
        x, womT, ob, mb, offs, mask);
    deformgemm_kernel<<<dim3(HH, BB), dim3(256), 0, stream>>>(
        x, wbfT, offs, mask, out);
}

// Round 3
// 111.292 us; speedup vs baseline: 3.3509x; 1.8397x over previous
//
#include <hip/hip_runtime.h>
#include <math.h>

#define BB 4
#define CC 64
#define OO 64
#define HH 128
#define WW 128
#define HWsz (HH * WW)

typedef __attribute__((ext_vector_type(8))) short short8;
typedef __attribute__((ext_vector_type(4))) float floatx4;

// fp32 -> bf16 round-to-nearest-even
static __device__ __forceinline__ short f2bf(float f) {
    union { float f; unsigned u; } v; v.f = f;
    unsigned r = (v.u + 0x7fffu + ((v.u >> 16) & 1u)) >> 16;
    return (short)r;
}
static __device__ __forceinline__ float bf2f(short s) {
    union { unsigned u; float f; } v;
    v.u = ((unsigned)(unsigned short)s) << 16;
    return v.f;
}

// 16B-granule XOR swizzle for Bt[64 px][64 c] bf16.
// slot16 = c>>3 (8 slots/row), swizzled slot = slot16 ^ (px & 7).
// Every aligned 8-channel fragment is one ds_read_b128 / ds_write_b128.
static __device__ __forceinline__ int bt_idx(int px, int c) {
    return px * 64 + ((((c >> 3) ^ (px & 7)) << 3) | (c & 7));
}

// ---------------------------------------------------------------------------
// prep: bf16 weight repack, K reordered [k][c] (k = tap).
//   wbfT[o*576 + k*64 + c] = bf16(weight[o][c][k])          (64 rows)
//   womT[o*576 + k*64 + c] = offset(18)/mask(9) weights, 32 rows zero-padded
// ---------------------------------------------------------------------------
__global__ __launch_bounds__(256) void prep_kernel(
    const float* __restrict__ wgt, const float* __restrict__ ow,
    const float* __restrict__ mw, short* __restrict__ wbfT,
    short* __restrict__ womT)
{
    int i = blockIdx.x * 256 + threadIdx.x;
    if (i < 64 * 576) {
        int o = i / 576, r = i % 576;
        int k = r >> 6, c = r & 63;
        wbfT[i] = f2bf(wgt[o * 576 + c * 9 + k]);
    } else if (i < 64 * 576 + 32 * 576) {
        int j = i - 64 * 576;
        int o = j / 576, r = j % 576;
        int k = r >> 6, c = r & 63;
        float v = 0.0f;
        if (o < 18) v = ow[o * 576 + c * 9 + k];
        else if (o < 27) v = mw[(o - 18) * 576 + c * 9 + k];
        womT[j] = f2bf(v);
    }
}

// ---------------------------------------------------------------------------
// nhwc: x NCHW f32 -> xh NHWC bf16 (xh[b][y][x][c]); one bilinear corner
// becomes one fully-used 128B line.
// ---------------------------------------------------------------------------
__global__ __launch_bounds__(256) void nhwc_kernel(
    const float* __restrict__ x, short* __restrict__ xh)
{
    int y = blockIdx.x, b = blockIdx.y;
    int tid = threadIdx.x;
    int px = tid & 127;
    int ch = (tid >> 7) * 32;
    const float* xp = x + (size_t)(b * CC + ch) * HWsz + y * WW + px;
    short buf[32];
#pragma unroll
    for (int q = 0; q < 32; ++q)
        buf[q] = f2bf(xp[(size_t)q * HWsz]);
    short* dst = xh + ((size_t)(b * HH + y) * WW + px) * 64 + ch;
#pragma unroll
    for (int q = 0; q < 4; ++q)
        *(short8*)&dst[q * 8] = *(const short8*)&buf[q * 8];
}

// ---------------------------------------------------------------------------
// fused: per block (64 px of one row, one image):
//   phase 1: 27-ch offset/mask conv via MFMA -> om[] in LDS (bias+sigmoid)
//   phase 2: bilinear sample (mask folded into corner weights) -> swizzled
//            LDS bf16 tile -> MFMA contraction -> out
// ---------------------------------------------------------------------------
__global__ __launch_bounds__(256, 4) void fused_kernel(
    const short* __restrict__ xh, const short* __restrict__ wbfT,
    const short* __restrict__ womT, const float* __restrict__ ob,
    const float* __restrict__ mb, float* __restrict__ out)
{
    __shared__ __align__(16) short Bt[64 * 64];
    __shared__ float om[27 * 65];

    int tid = threadIdx.x;
    int b = blockIdx.y, bx = blockIdx.x;
    int h = bx >> 1;
    int p0x = (bx & 1) * 64;
    int px = tid & 63;        // lane id == local pixel (sampling role)
    int eg = tid >> 6;        // wave id == channel group / MFMA px-tile
    int lane = px;

    const short* xhb = xh + (size_t)b * HWsz * 64;

    // ---------------- phase 1: offset/mask conv ----------------
    floatx4 accC[2];
    accC[0] = (floatx4){0.f, 0.f, 0.f, 0.f};
    accC[1] = (floatx4){0.f, 0.f, 0.f, 0.f};

#pragma unroll 1
    for (int k = 0; k < 9; ++k) {
        int ky = k / 3, kx = k % 3;
        int yy = h + ky - 1;
        int xx = p0x + px + kx - 1;
        bool valid = (yy >= 0) & (yy < HH) & (xx >= 0) & (xx < WW);
        short8 lo = {0, 0, 0, 0, 0, 0, 0, 0};
        short8 hi = {0, 0, 0, 0, 0, 0, 0, 0};
        if (valid) {
            const short* g = &xhb[((size_t)yy * WW + xx) * 64 + eg * 16];
            lo = *(const short8*)g;
            hi = *(const short8*)(g + 8);
        }
        __syncthreads();
        *(short8*)&Bt[bt_idx(px, eg * 16)] = lo;
        *(short8*)&Bt[bt_idx(px, eg * 16 + 8)] = hi;
        __syncthreads();
#pragma unroll
        for (int kh = 0; kh < 2; ++kh) {
            short8 bfrag = *(const short8*)
                &Bt[bt_idx(eg * 16 + (lane & 15), kh * 32 + (lane >> 4) * 8)];
#pragma unroll
            for (int m = 0; m < 2; ++m) {
                short8 afrag = *(const short8*)
                    &womT[(m * 16 + (lane & 15)) * 576 + k * 64 + kh * 32 + (lane >> 4) * 8];
                accC[m] = __builtin_amdgcn_mfma_f32_16x16x32_bf16(
                    afrag, bfrag, accC[m], 0, 0, 0);
            }
        }
    }
#pragma unroll
    for (int m = 0; m < 2; ++m)
#pragma unroll
        for (int j = 0; j < 4; ++j) {
            int o = m * 16 + (lane >> 4) * 4 + j;
            int pxe = eg * 16 + (lane & 15);
            float v = accC[m][j];
            if (o < 18) om[o * 65 + pxe] = v + ob[o];
            else if (o < 27) om[o * 65 + pxe] = 1.0f / (1.0f + expf(-(v + mb[o - 18])));
        }
    __syncthreads();

    // ---------------- phase 2: deformable sampling + GEMM ----------------
    floatx4 acc[4];
#pragma unroll
    for (int m = 0; m < 4; ++m) acc[m] = (floatx4){0.f, 0.f, 0.f, 0.f};

#pragma unroll 1
    for (int k = 0; k < 9; ++k) {
        int ky = k / 3, kx = k % 3;
        float oy = om[(2 * k) * 65 + px];
        float ox = om[(2 * k + 1) * 65 + px];
        float mk = om[(18 + k) * 65 + px];

        float py  = oy + (float)(h + ky - 1);
        float pxf = ox + (float)(p0x + px + kx - 1);
        float y0f = floorf(py), x0f = floorf(pxf);
        float dy = py - y0f, dx = pxf - x0f;
        int y0 = (int)y0f, x0 = (int)x0f;
        int y1 = y0 + 1, x1 = x0 + 1;

        bool vy0 = (y0 >= 0) & (y0 < HH);
        bool vy1 = (y1 >= 0) & (y1 < HH);
        bool vx0 = (x0 >= 0) & (x0 < WW);
        bool vx1 = (x1 >= 0) & (x1 < WW);
        float w00 = (vy0 & vx0) ? (1.0f - dy) * (1.0f - dx) * mk : 0.0f;
        float w01 = (vy0 & vx1) ? (1.0f - dy) * dx * mk : 0.0f;
        float w10 = (vy1 & vx0) ? dy * (1.0f - dx) * mk : 0.0f;
        float w11 = (vy1 & vx1) ? dy * dx * mk : 0.0f;

        int yc0 = min(max(y0, 0), HH - 1);
        int yc1 = min(max(y1, 0), HH - 1);
        int xc0 = min(max(x0, 0), WW - 1);
        int xc1 = min(max(x1, 0), WW - 1);

        const short* g00 = &xhb[((size_t)yc0 * WW + xc0) * 64 + eg * 16];
        const short* g01 = &xhb[((size_t)yc0 * WW + xc1) * 64 + eg * 16];
        const short* g10 = &xhb[((size_t)yc1 * WW + xc0) * 64 + eg * 16];
        const short* g11 = &xhb[((size_t)yc1 * WW + xc1) * 64 + eg * 16];
        short8 a0 = *(const short8*)g00, a1 = *(const short8*)(g00 + 8);
        short8 b0 = *(const short8*)g01, b1 = *(const short8*)(g01 + 8);
        short8 c0 = *(const short8*)g10, c1 = *(const short8*)(g10 + 8);
        short8 d0 = *(const short8*)g11, d1 = *(const short8*)(g11 + 8);

        short8 s0, s1;
#pragma unroll
        for (int j = 0; j < 8; ++j) {
            s0[j] = f2bf(w00 * bf2f(a0[j]) + w01 * bf2f(b0[j])
                       + w10 * bf2f(c0[j]) + w11 * bf2f(d0[j]));
            s1[j] = f2bf(w00 * bf2f(a1[j]) + w01 * bf2f(b1[j])
                       + w10 * bf2f(c1[j]) + w11 * bf2f(d1[j]));
        }
        __syncthreads();
        *(short8*)&Bt[bt_idx(px, eg * 16)] = s0;
        *(short8*)&Bt[bt_idx(px, eg * 16 + 8)] = s1;
        __syncthreads();

#pragma unroll
        for (int kh = 0; kh < 2; ++kh) {
            short8 bfrag = *(const short8*)
                &Bt[bt_idx(eg * 16 + (lane & 15), kh * 32 + (lane >> 4) * 8)];
#pragma unroll
            for (int m = 0; m < 4; ++m) {
                short8 afrag = *(const short8*)
                    &wbfT[(m * 16 + (lane & 15)) * 576 + k * 64 + kh * 32 + (lane >> 4) * 8];
                acc[m] = __builtin_amdgcn_mfma_f32_16x16x32_bf16(
                    afrag, bfrag, acc[m], 0, 0, 0);
            }
        }
    }

    // epilogue: row o, col = global px
    float* outp = out + (size_t)b * OO * HWsz + h * WW + p0x + eg * 16 + (lane & 15);
#pragma unroll
    for (int m = 0; m < 4; ++m)
#pragma unroll
        for (int j = 0; j < 4; ++j) {
            int o = m * 16 + (lane >> 4) * 4 + j;
            outp[(size_t)o * HWsz] = acc[m][j];
        }
}

extern "C" void kernel_launch(void* const* d_in, const int* in_sizes, int n_in,
                              void* d_out, int out_size, void* d_ws, size_t ws_size,
                              hipStream_t stream)
{
    const float* x   = (const float*)d_in[0];
    const float* ow  = (const float*)d_in[1];
    const float* ob  = (const float*)d_in[2];
    const float* mw  = (const float*)d_in[3];
    const float* mb  = (const float*)d_in[4];
    const float* wgt = (const float*)d_in[5];
    float* out = (float*)d_out;

    // ws: xh (4*16384*64 bf16 = 8.39MB) | wbfT (64*576) | womT (32*576)
    short* xh   = (short*)d_ws;
    short* wbfT = xh + (size_t)BB * HWsz * 64;
    short* womT = wbfT + 64 * 576;

    prep_kernel<<<dim3((64 * 576 + 32 * 576 + 255) / 256), dim3(256), 0, stream>>>(
        wgt, ow, mw, wbfT, womT);
    nhwc_kernel<<<dim3(HH, BB), dim3(256), 0, stream>>>(x, xh);
    fused_kernel<<<dim3(HH * 2, BB), dim3(256), 0, stream>>>(
        xh, wbfT, womT, ob, mb, out);
}

// Round 4
// 108.891 us; speedup vs baseline: 3.4248x; 1.0220x over previous
//
#include <hip/hip_runtime.h>
#include <hip/hip_bf16.h>
#include <math.h>

#define BB 4
#define CC 64
#define OO 64
#define HH 128
#define WW 128
#define HWsz (HH * WW)

typedef __attribute__((ext_vector_type(8))) short short8;
typedef __attribute__((ext_vector_type(4))) float floatx4;

static __device__ __forceinline__ short f2bf(float f) {
    __hip_bfloat16 h = __float2bfloat16(f);   // RNE; compiler can pack cvt_pk
    union { __hip_bfloat16 h; short s; } u; u.h = h; return u.s;
}
static __device__ __forceinline__ float bf2f(short s) {
    union { unsigned u; float f; } v;
    v.u = ((unsigned)(unsigned short)s) << 16;
    return v.f;
}

// ---------------------------------------------------------------------------
// prep: bf16 weight repack, K reordered [k][c] (k = tap).
//   wbfT[o*576 + k*64 + c] = bf16(weight[o][c][k])          (64 rows)
//   womT[o*576 + k*64 + c] = offset(18)/mask(9) rows, 32 rows zero-padded
// ---------------------------------------------------------------------------
__global__ __launch_bounds__(256) void prep_kernel(
    const float* __restrict__ wgt, const float* __restrict__ ow,
    const float* __restrict__ mw, short* __restrict__ wbfT,
    short* __restrict__ womT)
{
    int i = blockIdx.x * 256 + threadIdx.x;
    if (i < 64 * 576) {
        int o = i / 576, r = i % 576;
        int k = r >> 6, c = r & 63;
        wbfT[i] = f2bf(wgt[o * 576 + c * 9 + k]);
    } else if (i < 64 * 576 + 32 * 576) {
        int j = i - 64 * 576;
        int o = j / 576, r = j % 576;
        int k = r >> 6, c = r & 63;
        float v = 0.0f;
        if (o < 18) v = ow[o * 576 + c * 9 + k];
        else if (o < 27) v = mw[(o - 18) * 576 + c * 9 + k];
        womT[j] = f2bf(v);
    }
}

// ---------------------------------------------------------------------------
// nhwc: x NCHW f32 -> xh NHWC bf16 (one bilinear corner = one 128B line)
// ---------------------------------------------------------------------------
__global__ __launch_bounds__(256) void nhwc_kernel(
    const float* __restrict__ x, short* __restrict__ xh)
{
    int y = blockIdx.x, b = blockIdx.y;
    int tid = threadIdx.x;
    int px = tid & 127;
    int ch = (tid >> 7) * 32;
    const float* xp = x + (size_t)(b * CC + ch) * HWsz + y * WW + px;
    short buf[32];
#pragma unroll
    for (int q = 0; q < 32; ++q)
        buf[q] = f2bf(xp[(size_t)q * HWsz]);
    short* dst = xh + ((size_t)(b * HH + y) * WW + px) * 64 + ch;
#pragma unroll
    for (int q = 0; q < 4; ++q)
        *(short8*)&dst[q * 8] = *(const short8*)&buf[q * 8];
}

// ---------------------------------------------------------------------------
// fused: each wave independently owns 16 px of one row. No __syncthreads.
//   phase 1: offset/mask conv, im2col fragments straight from global ->
//            MFMA -> per-wave om[27][16] in LDS (bias + sigmoid)
//   phase 2: per tap, 4-corner gather into B-fragment registers, in-register
//            bilinear blend (mask folded), MFMA vs weight A-fragments.
//            Depth-1 pipeline: tap k+1 corner loads issued mid-tap-k.
// ---------------------------------------------------------------------------
__global__ __launch_bounds__(256, 4) void fused_kernel(
    const short* __restrict__ xh, const short* __restrict__ wbfT,
    const short* __restrict__ womT, const float* __restrict__ ob,
    const float* __restrict__ mb, float* __restrict__ out)
{
    __shared__ float om[4 * 32 * 16];   // per-wave 32x16 scratch (27 used)

    int tid = threadIdx.x;
    // XCD-bijective swizzle: 1024 blocks = 8 XCDs x 128 contiguous chunks
    int gid = blockIdx.y * gridDim.x + blockIdx.x;
    int sid = (gid & 7) * 128 + (gid >> 3);
    int b = sid >> 8;
    int r = sid & 255;
    int h = r >> 1;
    int p0 = (r & 1) << 6;

    int wv = tid >> 6;
    int lane = tid & 63;
    int g = lane >> 4;        // k-group (channel octet)
    int pl = lane & 15;       // px within the wave's 16-px strip
    int xw = p0 + wv * 16 + pl;   // this lane's column

    const short* xhb = xh + (size_t)b * HWsz * 64;
    float* omw = &om[wv * 32 * 16];

    // ---------------- phase 1: offset/mask conv ----------------
    floatx4 accC0 = {0.f, 0.f, 0.f, 0.f};
    floatx4 accC1 = {0.f, 0.f, 0.f, 0.f};
#pragma unroll
    for (int k = 0; k < 9; ++k) {
        int ky = k / 3, kx = k % 3;
        int yy = h + ky - 1;
        int xx = xw + kx - 1;
        bool valid = (yy >= 0) & (yy < HH) & (xx >= 0) & (xx < WW);
        short8 bf0 = {0, 0, 0, 0, 0, 0, 0, 0};
        short8 bf1 = {0, 0, 0, 0, 0, 0, 0, 0};
        if (valid) {
            const short* gp = xhb + (((size_t)yy * WW + xx) << 6) + g * 8;
            bf0 = *(const short8*)gp;
            bf1 = *(const short8*)(gp + 32);
        }
        const short* wp = womT + pl * 576 + k * 64 + g * 8;
        short8 a00 = *(const short8*)(wp);
        short8 a01 = *(const short8*)(wp + 32);
        short8 a10 = *(const short8*)(wp + 9216);
        short8 a11 = *(const short8*)(wp + 9216 + 32);
        accC0 = __builtin_amdgcn_mfma_f32_16x16x32_bf16(a00, bf0, accC0, 0, 0, 0);
        accC0 = __builtin_amdgcn_mfma_f32_16x16x32_bf16(a01, bf1, accC0, 0, 0, 0);
        accC1 = __builtin_amdgcn_mfma_f32_16x16x32_bf16(a10, bf0, accC1, 0, 0, 0);
        accC1 = __builtin_amdgcn_mfma_f32_16x16x32_bf16(a11, bf1, accC1, 0, 0, 0);
    }
#pragma unroll
    for (int j = 0; j < 4; ++j) {
        int o = g * 4 + j;                 // 0..15 -> offset rows
        omw[o * 16 + pl] = accC0[j] + ob[o];
        int o2 = 16 + g * 4 + j;           // 16..31
        float v = accC1[j];
        if (o2 < 18) omw[o2 * 16 + pl] = v + ob[o2];
        else if (o2 < 27)
            omw[o2 * 16 + pl] = 1.0f / (1.0f + expf(-(v + mb[o2 - 18])));
    }

    // ---------------- phase 2: sample + GEMM, depth-1 pipeline ----------
    auto mktap = [&](int k, int& j00, int& j01, int& j10, int& j11,
                     float& u00, float& u01, float& u10, float& u11) {
        int ky = k / 3, kx = k - ky * 3;
        float oy = omw[(2 * k) * 16 + pl];
        float ox = omw[(2 * k + 1) * 16 + pl];
        float mk = omw[(18 + k) * 16 + pl];
        float py = oy + (float)(h + ky - 1);
        float qx = ox + (float)(xw + kx - 1);
        float y0f = floorf(py), x0f = floorf(qx);
        float dy = py - y0f, dx = qx - x0f;
        int y0 = (int)y0f, x0 = (int)x0f;
        int y1 = y0 + 1, x1 = x0 + 1;
        bool vy0 = (y0 >= 0) & (y0 < HH), vy1 = (y1 >= 0) & (y1 < HH);
        bool vx0 = (x0 >= 0) & (x0 < WW), vx1 = (x1 >= 0) & (x1 < WW);
        u00 = (vy0 & vx0) ? (1.0f - dy) * (1.0f - dx) * mk : 0.0f;
        u01 = (vy0 & vx1) ? (1.0f - dy) * dx * mk : 0.0f;
        u10 = (vy1 & vx0) ? dy * (1.0f - dx) * mk : 0.0f;
        u11 = (vy1 & vx1) ? dy * dx * mk : 0.0f;
        int yc0 = min(max(y0, 0), HH - 1), yc1 = min(max(y1, 0), HH - 1);
        int xc0 = min(max(x0, 0), WW - 1), xc1 = min(max(x1, 0), WW - 1);
        j00 = ((yc0 * WW + xc0) << 6) + g * 8;
        j01 = ((yc0 * WW + xc1) << 6) + g * 8;
        j10 = ((yc1 * WW + xc0) << 6) + g * 8;
        j11 = ((yc1 * WW + xc1) << 6) + g * 8;
    };
    auto blend8 = [&](short8 r0, short8 r1, short8 r2, short8 r3,
                      float u00, float u01, float u10, float u11) -> short8 {
        short8 t;
#pragma unroll
        for (int j = 0; j < 8; ++j) {
            float s = u00 * bf2f(r0[j]);
            s += u01 * bf2f(r1[j]);
            s += u10 * bf2f(r2[j]);
            s += u11 * bf2f(r3[j]);
            t[j] = f2bf(s);
        }
        return t;
    };

    floatx4 acc[4];
#pragma unroll
    for (int m = 0; m < 4; ++m) acc[m] = (floatx4){0.f, 0.f, 0.f, 0.f};

    int i00, i01, i10, i11;
    float w00, w01, w10, w11;
    mktap(0, i00, i01, i10, i11, w00, w01, w10, w11);
    short8 c00 = *(const short8*)(xhb + i00);
    short8 c01 = *(const short8*)(xhb + i01);
    short8 c10 = *(const short8*)(xhb + i10);
    short8 c11 = *(const short8*)(xhb + i11);

#pragma unroll 1
    for (int k = 0; k < 9; ++k) {
        // kh=1 corner loads of current tap (upper 32 channels)
        short8 d00 = *(const short8*)(xhb + i00 + 32);
        short8 d01 = *(const short8*)(xhb + i01 + 32);
        short8 d10 = *(const short8*)(xhb + i10 + 32);
        short8 d11 = *(const short8*)(xhb + i11 + 32);
        // weight fragments for this tap
        const short* wp = wbfT + pl * 576 + k * 64 + g * 8;
        short8 a0k0 = *(const short8*)(wp);
        short8 a1k0 = *(const short8*)(wp + 9216);
        short8 a2k0 = *(const short8*)(wp + 18432);
        short8 a3k0 = *(const short8*)(wp + 27648);
        short8 a0k1 = *(const short8*)(wp + 32);
        short8 a1k1 = *(const short8*)(wp + 9216 + 32);
        short8 a2k1 = *(const short8*)(wp + 18432 + 32);
        short8 a3k1 = *(const short8*)(wp + 27648 + 32);

        short8 bf0 = blend8(c00, c01, c10, c11, w00, w01, w10, w11);
        acc[0] = __builtin_amdgcn_mfma_f32_16x16x32_bf16(a0k0, bf0, acc[0], 0, 0, 0);
        acc[1] = __builtin_amdgcn_mfma_f32_16x16x32_bf16(a1k0, bf0, acc[1], 0, 0, 0);
        acc[2] = __builtin_amdgcn_mfma_f32_16x16x32_bf16(a2k0, bf0, acc[2], 0, 0, 0);
        acc[3] = __builtin_amdgcn_mfma_f32_16x16x32_bf16(a3k0, bf0, acc[3], 0, 0, 0);

        // prefetch next tap's params + lower-32ch corners
        int n00 = i00, n01 = i01, n10 = i10, n11 = i11;
        float v00 = w00, v01 = w01, v10 = w10, v11 = w11;
        if (k < 8) {
            mktap(k + 1, n00, n01, n10, n11, v00, v01, v10, v11);
            c00 = *(const short8*)(xhb + n00);
            c01 = *(const short8*)(xhb + n01);
            c10 = *(const short8*)(xhb + n10);
            c11 = *(const short8*)(xhb + n11);
        }

        short8 bf1 = blend8(d00, d01, d10, d11, w00, w01, w10, w11);
        acc[0] = __builtin_amdgcn_mfma_f32_16x16x32_bf16(a0k1, bf1, acc[0], 0, 0, 0);
        acc[1] = __builtin_amdgcn_mfma_f32_16x16x32_bf16(a1k1, bf1, acc[1], 0, 0, 0);
        acc[2] = __builtin_amdgcn_mfma_f32_16x16x32_bf16(a2k1, bf1, acc[2], 0, 0, 0);
        acc[3] = __builtin_amdgcn_mfma_f32_16x16x32_bf16(a3k1, bf1, acc[3], 0, 0, 0);

        i00 = n00; i01 = n01; i10 = n10; i11 = n11;
        w00 = v00; w01 = v01; w10 = v10; w11 = v11;
    }

    // epilogue: D col = pl (this lane's px), row o = m*16 + g*4 + j
    float* outp = out + (size_t)b * OO * HWsz + h * WW + p0 + wv * 16 + pl;
#pragma unroll
    for (int m = 0; m < 4; ++m)
#pragma unroll
        for (int j = 0; j < 4; ++j) {
            int o = m * 16 + g * 4 + j;
            outp[(size_t)o * HWsz] = acc[m][j];
        }
}

extern "C" void kernel_launch(void* const* d_in, const int* in_sizes, int n_in,
                              void* d_out, int out_size, void* d_ws, size_t ws_size,
                              hipStream_t stream)
{
    const float* x   = (const float*)d_in[0];
    const float* ow  = (const float*)d_in[1];
    const float* ob  = (const float*)d_in[2];
    const float* mw  = (const float*)d_in[3];
    const float* mb  = (const float*)d_in[4];
    const float* wgt = (const float*)d_in[5];
    float* out = (float*)d_out;

    // ws: xh (4*16384*64 bf16 = 8.39MB) | wbfT (64*576) | womT (32*576)
    short* xh   = (short*)d_ws;
    short* wbfT = xh + (size_t)BB * HWsz * 64;
    short* womT = wbfT + 64 * 576;

    prep_kernel<<<dim3((64 * 576 + 32 * 576 + 255) / 256), dim3(256), 0, stream>>>(
        wgt, ow, mw, wbfT, womT);
    nhwc_kernel<<<dim3(HH, BB), dim3(256), 0, stream>>>(x, xh);
    fused_kernel<<<dim3(HH * 2, BB), dim3(256), 0, stream>>>(
        xh, wbfT, womT, ob, mb, out);
}

// Round 5
// 70.845 us; speedup vs baseline: 5.2640x; 1.5370x over previous
//
#include <hip/hip_runtime.h>
#include <hip/hip_bf16.h>
#include <math.h>

#define BB 4
#define CC 64
#define OO 64
#define HH 128
#define WW 128
#define HWsz (HH * WW)

typedef __attribute__((ext_vector_type(8))) short short8;
typedef __attribute__((ext_vector_type(4))) float floatx4;

static __device__ __forceinline__ short f2bf(float f) {
    __hip_bfloat16 h = __float2bfloat16(f);   // RNE
    union { __hip_bfloat16 h; short s; } u; u.h = h; return u.s;
}
static __device__ __forceinline__ float bf2f(short s) {
    union { unsigned u; float f; } v;
    v.u = ((unsigned)(unsigned short)s) << 16;
    return v.f;
}

// ---------------------------------------------------------------------------
// prep: fragment-ordered, lane-coalesced weight layouts.
//  waf[((k*2+kh)*4+m)*512 + lane*8 + j] =
//      bf16(wgt[(m*16+(lane&15))*576 + (kh*32+(lane>>4)*8+j)*9 + k])
//  wcf[((k*2+kh)*2+m)*512 + lane*8 + j] = offset(18)/mask(9) rows, 0-padded
// ---------------------------------------------------------------------------
__global__ __launch_bounds__(256) void prep_kernel(
    const float* __restrict__ wgt, const float* __restrict__ ow,
    const float* __restrict__ mw, short* __restrict__ waf,
    short* __restrict__ wcf)
{
    int i = blockIdx.x * 256 + threadIdx.x;
    if (i < 36864) {
        int j = i & 7, lane = (i >> 3) & 63, rest = i >> 9;
        int m = rest & 3, kh = (rest >> 2) & 1, k = rest >> 3;
        int o = m * 16 + (lane & 15);
        int c = kh * 32 + ((lane >> 4) << 3) + j;
        waf[i] = f2bf(wgt[o * 576 + c * 9 + k]);
    } else if (i < 55296) {
        int t = i - 36864;
        int j = t & 7, lane = (t >> 3) & 63, rest = t >> 9;
        int m = rest & 1, kh = (rest >> 1) & 1, k = rest >> 2;
        int o = m * 16 + (lane & 15);
        int c = kh * 32 + ((lane >> 4) << 3) + j;
        float v = 0.f;
        if (o < 18) v = ow[o * 576 + c * 9 + k];
        else if (o < 27) v = mw[(o - 18) * 576 + c * 9 + k];
        wcf[t] = f2bf(v);
    }
}

// ---------------------------------------------------------------------------
// nhwc: x NCHW f32 -> xh NHWC bf16 (one bilinear corner = one 128B line)
// ---------------------------------------------------------------------------
__global__ __launch_bounds__(256) void nhwc_kernel(
    const float* __restrict__ x, short* __restrict__ xh)
{
    int y = blockIdx.x, b = blockIdx.y;
    int tid = threadIdx.x;
    int px = tid & 127;
    int ch = (tid >> 7) * 32;
    const float* xp = x + (size_t)(b * CC + ch) * HWsz + y * WW + px;
    short buf[32];
#pragma unroll
    for (int q = 0; q < 32; ++q)
        buf[q] = f2bf(xp[(size_t)q * HWsz]);
    short* dst = xh + ((size_t)(b * HH + y) * WW + px) * 64 + ch;
#pragma unroll
    for (int q = 0; q < 4; ++q)
        *(short8*)&dst[q * 8] = *(const short8*)&buf[q * 8];
}

// ---------------------------------------------------------------------------
// fused kernel. Per block: 64 px of one row. 4 waves, each owning 16 px.
//   entry:   issue waf->reg staging loads (latency hidden under phase 1)
//   phase 1: offset/mask conv (pair-pipelined, coalesced wcf weights) -> om
//   stage:   reg -> LDS weight store, one __syncthreads
//   phase 2: per tap: full 8-load corner prefetch of next tap, in-register
//            bilinear blend (mask folded), weights via ds_read_b128, MFMA.
// ---------------------------------------------------------------------------
__global__ __launch_bounds__(256, 2) void fused_kernel(
    const short* __restrict__ xh, const short* __restrict__ waf,
    const short* __restrict__ wcf, const float* __restrict__ ob,
    const float* __restrict__ mb, float* __restrict__ out)
{
    __shared__ __align__(16) short lds_waf[36864];   // 73728 B
    __shared__ float om[4 * 27 * 16];                //  6912 B

    int tid = threadIdx.x;
    int gid = blockIdx.x;
    // XCD-bijective swizzle: 1024 blocks = 8 XCDs x 128 contiguous
    int sid = (gid & 7) * 128 + (gid >> 3);
    int b = sid >> 8;
    int r = sid & 255;
    int h = r >> 1;
    int p0 = (r & 1) << 6;

    int wv = tid >> 6;
    int lane = tid & 63;
    int g = lane >> 4;
    int pl = lane & 15;
    int goff = g * 8;
    int xw = p0 + wv * 16 + pl;

    const short* xhb = xh + ((size_t)b << 20);
    float* omw = &om[wv * 27 * 16];

    // ---- issue weight staging loads into registers (written to LDS later)
    short8 stg[18];
#pragma unroll
    for (int i = 0; i < 18; ++i)
        stg[i] = *(const short8*)(waf + ((wv * 18 + i) << 9) + lane * 8);

    // ---------------- phase 1: offset/mask conv (pipelined) ----------------
    floatx4 accC0 = {0.f, 0.f, 0.f, 0.f};
    floatx4 accC1 = {0.f, 0.f, 0.f, 0.f};

#define CADDR(K, P, V) do {                                                  \
    int ky = (K) / 3, kx = (K) - ky * 3;                                     \
    int yy = h + ky - 1, xx = xw + kx - 1;                                   \
    V = (yy >= 0) & (yy < HH) & (xx >= 0) & (xx < WW);                       \
    int yc = min(max(yy, 0), HH - 1), xc = min(max(xx, 0), WW - 1);          \
    P = ((yc * WW + xc) << 6) + goff;                                        \
} while (0)

#define CONVTAP(K, S0, S1, V) do {                                           \
    const short* wp = wcf + ((K) << 11) + lane * 8;                          \
    short8 w00 = *(const short8*)(wp + (0 << 9));                            \
    short8 w01 = *(const short8*)(wp + (1 << 9));                            \
    short8 w10 = *(const short8*)(wp + (2 << 9));                            \
    short8 w11 = *(const short8*)(wp + (3 << 9));                            \
    short8 z = {0, 0, 0, 0, 0, 0, 0, 0};                                     \
    short8 a0 = S0, a1 = S1;                                                 \
    if (!(V)) { a0 = z; a1 = z; }                                            \
    accC0 = __builtin_amdgcn_mfma_f32_16x16x32_bf16(w00, a0, accC0, 0, 0, 0);\
    accC1 = __builtin_amdgcn_mfma_f32_16x16x32_bf16(w01, a0, accC1, 0, 0, 0);\
    accC0 = __builtin_amdgcn_mfma_f32_16x16x32_bf16(w10, a1, accC0, 0, 0, 0);\
    accC1 = __builtin_amdgcn_mfma_f32_16x16x32_bf16(w11, a1, accC1, 0, 0, 0);\
} while (0)

    {
        bool vA, vB;
        int pa, pb;
        short8 A0, A1, B0, B1;
        CADDR(0, pa, vA);
        A0 = *(const short8*)(xhb + pa);
        A1 = *(const short8*)(xhb + pa + 32);
#pragma unroll 1
        for (int kp = 0; kp < 4; ++kp) {
            int k = kp * 2;
            CADDR(k + 1, pb, vB);
            B0 = *(const short8*)(xhb + pb);
            B1 = *(const short8*)(xhb + pb + 32);
            CONVTAP(k, A0, A1, vA);
            CADDR(k + 2, pa, vA);
            A0 = *(const short8*)(xhb + pa);
            A1 = *(const short8*)(xhb + pa + 32);
            CONVTAP(k + 1, B0, B1, vB);
        }
        CONVTAP(8, A0, A1, vA);
    }

    // om epilogue (wave-local LDS, no barrier needed yet)
#pragma unroll
    for (int j = 0; j < 4; ++j) {
        int o = g * 4 + j;
        omw[o * 16 + pl] = accC0[j] + ob[o];
        int o2 = 16 + g * 4 + j;
        float v = accC1[j];
        if (o2 < 18) omw[o2 * 16 + pl] = v + ob[o2];
        else if (o2 < 27)
            omw[o2 * 16 + pl] = 1.0f / (1.0f + expf(-(v + mb[o2 - 18])));
    }

    // ---- weights reg -> LDS, single barrier
#pragma unroll
    for (int i = 0; i < 18; ++i)
        *(short8*)&lds_waf[((wv * 18 + i) << 9) + lane * 8] = stg[i];
    __syncthreads();

    // ---------------- phase 2: deformable sampling + GEMM ----------------
    floatx4 acc0 = {0.f, 0.f, 0.f, 0.f}, acc1 = {0.f, 0.f, 0.f, 0.f};
    floatx4 acc2 = {0.f, 0.f, 0.f, 0.f}, acc3 = {0.f, 0.f, 0.f, 0.f};

#define MKTAP(K, I00, I01, I10, I11, U00, U01, U10, U11) do {                \
    int ky = (K) / 3, kx = (K) - ky * 3;                                     \
    float oy = omw[(2 * (K)) * 16 + pl];                                     \
    float ox = omw[(2 * (K) + 1) * 16 + pl];                                 \
    float mk = omw[(18 + (K)) * 16 + pl];                                    \
    float py = oy + (float)(h + ky - 1);                                     \
    float qx = ox + (float)(xw + kx - 1);                                    \
    float y0f = floorf(py), x0f = floorf(qx);                                \
    float dyy = py - y0f, dxx = qx - x0f;                                    \
    int y0 = (int)y0f, x0 = (int)x0f;                                        \
    int y1 = y0 + 1, x1 = x0 + 1;                                            \
    bool vy0 = (y0 >= 0) & (y0 < HH), vy1 = (y1 >= 0) & (y1 < HH);           \
    bool vx0 = (x0 >= 0) & (x0 < WW), vx1 = (x1 >= 0) & (x1 < WW);           \
    U00 = (vy0 & vx0) ? (1.f - dyy) * (1.f - dxx) * mk : 0.f;                \
    U01 = (vy0 & vx1) ? (1.f - dyy) * dxx * mk : 0.f;                        \
    U10 = (vy1 & vx0) ? dyy * (1.f - dxx) * mk : 0.f;                        \
    U11 = (vy1 & vx1) ? dyy * dxx * mk : 0.f;                                \
    int yc0 = min(max(y0, 0), HH - 1), yc1 = min(max(y1, 0), HH - 1);        \
    int xc0 = min(max(x0, 0), WW - 1), xc1 = min(max(x1, 0), WW - 1);        \
    I00 = ((yc0 * WW + xc0) << 6) + goff;                                    \
    I01 = ((yc0 * WW + xc1) << 6) + goff;                                    \
    I10 = ((yc1 * WW + xc0) << 6) + goff;                                    \
    I11 = ((yc1 * WW + xc1) << 6) + goff;                                    \
} while (0)

#define ISSUE8(I00, I01, I10, I11, C00, C01, C10, C11, D00, D01, D10, D11) do { \
    C00 = *(const short8*)(xhb + I00); C01 = *(const short8*)(xhb + I01);    \
    C10 = *(const short8*)(xhb + I10); C11 = *(const short8*)(xhb + I11);    \
    D00 = *(const short8*)(xhb + I00 + 32); D01 = *(const short8*)(xhb + I01 + 32); \
    D10 = *(const short8*)(xhb + I10 + 32); D11 = *(const short8*)(xhb + I11 + 32); \
} while (0)

#define BLEND(T, R0, R1, R2, R3, U00, U01, U10, U11) do {                    \
    _Pragma("unroll") for (int jj = 0; jj < 8; ++jj) {                       \
        float s = U00 * bf2f(R0[jj]) + U01 * bf2f(R1[jj])                    \
                + U10 * bf2f(R2[jj]) + U11 * bf2f(R3[jj]);                   \
        T[jj] = f2bf(s);                                                     \
    }                                                                        \
} while (0)

#define TAPMFMA(K, C00, C01, C10, C11, D00, D01, D10, D11, U00, U01, U10, U11) do { \
    const short* wk = &lds_waf[((K) << 12) + lane * 8];                      \
    short8 q0 = *(const short8*)(wk + (0 << 9));                             \
    short8 q1 = *(const short8*)(wk + (1 << 9));                             \
    short8 q2 = *(const short8*)(wk + (2 << 9));                             \
    short8 q3 = *(const short8*)(wk + (3 << 9));                             \
    short8 bf;                                                               \
    BLEND(bf, C00, C01, C10, C11, U00, U01, U10, U11);                       \
    acc0 = __builtin_amdgcn_mfma_f32_16x16x32_bf16(q0, bf, acc0, 0, 0, 0);   \
    acc1 = __builtin_amdgcn_mfma_f32_16x16x32_bf16(q1, bf, acc1, 0, 0, 0);   \
    acc2 = __builtin_amdgcn_mfma_f32_16x16x32_bf16(q2, bf, acc2, 0, 0, 0);   \
    acc3 = __builtin_amdgcn_mfma_f32_16x16x32_bf16(q3, bf, acc3, 0, 0, 0);   \
    q0 = *(const short8*)(wk + (4 << 9));                                    \
    q1 = *(const short8*)(wk + (5 << 9));                                    \
    q2 = *(const short8*)(wk + (6 << 9));                                    \
    q3 = *(const short8*)(wk + (7 << 9));                                    \
    BLEND(bf, D00, D01, D10, D11, U00, U01, U10, U11);                       \
    acc0 = __builtin_amdgcn_mfma_f32_16x16x32_bf16(q0, bf, acc0, 0, 0, 0);   \
    acc1 = __builtin_amdgcn_mfma_f32_16x16x32_bf16(q1, bf, acc1, 0, 0, 0);   \
    acc2 = __builtin_amdgcn_mfma_f32_16x16x32_bf16(q2, bf, acc2, 0, 0, 0);   \
    acc3 = __builtin_amdgcn_mfma_f32_16x16x32_bf16(q3, bf, acc3, 0, 0, 0);   \
} while (0)

    {
        int iA00, iA01, iA10, iA11, iB00, iB01, iB10, iB11;
        float uA00, uA01, uA10, uA11, uB00, uB01, uB10, uB11;
        short8 cA00, cA01, cA10, cA11, dA00, dA01, dA10, dA11;
        short8 cB00, cB01, cB10, cB11, dB00, dB01, dB10, dB11;

        MKTAP(0, iA00, iA01, iA10, iA11, uA00, uA01, uA10, uA11);
        ISSUE8(iA00, iA01, iA10, iA11, cA00, cA01, cA10, cA11, dA00, dA01, dA10, dA11);
#pragma unroll 1
        for (int kp = 0; kp < 4; ++kp) {
            int k = kp * 2;
            MKTAP(k + 1, iB00, iB01, iB10, iB11, uB00, uB01, uB10, uB11);
            ISSUE8(iB00, iB01, iB10, iB11, cB00, cB01, cB10, cB11, dB00, dB01, dB10, dB11);
            TAPMFMA(k, cA00, cA01, cA10, cA11, dA00, dA01, dA10, dA11,
                    uA00, uA01, uA10, uA11);
            MKTAP(k + 2, iA00, iA01, iA10, iA11, uA00, uA01, uA10, uA11);
            ISSUE8(iA00, iA01, iA10, iA11, cA00, cA01, cA10, cA11, dA00, dA01, dA10, dA11);
            TAPMFMA(k + 1, cB00, cB01, cB10, cB11, dB00, dB01, dB10, dB11,
                    uB00, uB01, uB10, uB11);
        }
        TAPMFMA(8, cA00, cA01, cA10, cA11, dA00, dA01, dA10, dA11,
                uA00, uA01, uA10, uA11);
    }

    // epilogue: D col = pl, row o = m*16 + g*4 + j
    float* outp = out + (size_t)b * OO * HWsz + h * WW + p0 + wv * 16 + pl;
#pragma unroll
    for (int j = 0; j < 4; ++j) outp[(size_t)(g * 4 + j) * HWsz] = acc0[j];
#pragma unroll
    for (int j = 0; j < 4; ++j) outp[(size_t)(16 + g * 4 + j) * HWsz] = acc1[j];
#pragma unroll
    for (int j = 0; j < 4; ++j) outp[(size_t)(32 + g * 4 + j) * HWsz] = acc2[j];
#pragma unroll
    for (int j = 0; j < 4; ++j) outp[(size_t)(48 + g * 4 + j) * HWsz] = acc3[j];
}

extern "C" void kernel_launch(void* const* d_in, const int* in_sizes, int n_in,
                              void* d_out, int out_size, void* d_ws, size_t ws_size,
                              hipStream_t stream)
{
    const float* x   = (const float*)d_in[0];
    const float* ow  = (const float*)d_in[1];
    const float* ob  = (const float*)d_in[2];
    const float* mw  = (const float*)d_in[3];
    const float* mb  = (const float*)d_in[4];
    const float* wgt = (const float*)d_in[5];
    float* out = (float*)d_out;

    // ws: xh (4*16384*64 bf16 = 8.39MB) | waf (36864 bf16) | wcf (18432 bf16)
    short* xh  = (short*)d_ws;
    short* waf = xh + (size_t)BB * HWsz * 64;
    short* wcf = waf + 36864;

    prep_kernel<<<dim3(216), dim3(256), 0, stream>>>(wgt, ow, mw, waf, wcf);
    nhwc_kernel<<<dim3(HH, BB), dim3(256), 0, stream>>>(x, xh);
    fused_kernel<<<dim3(1024), dim3(256), 0, stream>>>(
        xh, waf, wcf, ob, mb, out);
}

// Round 6
// 68.584 us; speedup vs baseline: 5.4375x; 1.0330x over previous
//
#include <hip/hip_runtime.h>
#include <hip/hip_bf16.h>
#include <math.h>

#define BB 4
#define CC 64
#define OO 64
#define HH 128
#define WW 128
#define HWsz (HH * WW)

typedef __attribute__((ext_vector_type(8))) short short8;
typedef __attribute__((ext_vector_type(4))) float floatx4;

static __device__ __forceinline__ short f2bf(float f) {
    __hip_bfloat16 h = __float2bfloat16(f);   // RNE
    union { __hip_bfloat16 h; short s; } u; u.h = h; return u.s;
}
static __device__ __forceinline__ float bf2f(short s) {
    union { unsigned u; float f; } v;
    v.u = ((unsigned)(unsigned short)s) << 16;
    return v.f;
}

// ---------------------------------------------------------------------------
// pre: (blocks 0..511)  x NCHW f32 -> xh NHWC bf16
//      (blocks 512..727) fragment-ordered weight repack:
//  waf[((k*2+kh)*4+m)*512 + lane*8 + j] =
//      bf16(wgt[(m*16+(lane&15))*576 + (kh*32+(lane>>4)*8+j)*9 + k])
//  wcf[((k*2+kh)*2+m)*512 + lane*8 + j] = offset(18)/mask(9) rows, 0-padded
// ---------------------------------------------------------------------------
__global__ __launch_bounds__(256) void pre_kernel(
    const float* __restrict__ x, const float* __restrict__ wgt,
    const float* __restrict__ ow, const float* __restrict__ mw,
    short* __restrict__ xh, short* __restrict__ waf, short* __restrict__ wcf)
{
    int bid = blockIdx.x;
    int tid = threadIdx.x;
    if (bid < 512) {
        int b = bid >> 7, y = bid & 127;
        int px = tid & 127;
        int ch = (tid >> 7) * 32;
        const float* xp = x + (size_t)(b * CC + ch) * HWsz + y * WW + px;
        short buf[32];
#pragma unroll
        for (int q = 0; q < 32; ++q)
            buf[q] = f2bf(xp[(size_t)q * HWsz]);
        short* dst = xh + ((size_t)(b * HH + y) * WW + px) * 64 + ch;
#pragma unroll
        for (int q = 0; q < 4; ++q)
            *(short8*)&dst[q * 8] = *(const short8*)&buf[q * 8];
    } else {
        int i = (bid - 512) * 256 + tid;
        if (i < 36864) {
            int j = i & 7, lane = (i >> 3) & 63, rest = i >> 9;
            int m = rest & 3, kh = (rest >> 2) & 1, k = rest >> 3;
            int o = m * 16 + (lane & 15);
            int c = kh * 32 + ((lane >> 4) << 3) + j;
            waf[i] = f2bf(wgt[o * 576 + c * 9 + k]);
        } else if (i < 55296) {
            int t = i - 36864;
            int j = t & 7, lane = (t >> 3) & 63, rest = t >> 9;
            int m = rest & 1, kh = (rest >> 1) & 1, k = rest >> 2;
            int o = m * 16 + (lane & 15);
            int c = kh * 32 + ((lane >> 4) << 3) + j;
            float v = 0.f;
            if (o < 18) v = ow[o * 576 + c * 9 + k];
            else if (o < 27) v = mw[(o - 18) * 576 + c * 9 + k];
            wcf[t] = f2bf(v);
        }
    }
}

// ---------------------------------------------------------------------------
// fused kernel. Per block: 64 px of one row. 4 waves, each owning 16 px.
// No LDS weight staging (weights read from L1-hot global, fragment-ordered),
// no __syncthreads, 4 blocks/CU.
//   phase 1: offset/mask conv (pair-pipelined) -> om (wave-local LDS)
//   phase 2: per tap: 8-load corner prefetch of next tap, in-register
//            bilinear blend (mask folded), global weight fragments, MFMA.
// ---------------------------------------------------------------------------
__global__ __launch_bounds__(256, 4) void fused_kernel(
    const short* __restrict__ xh, const short* __restrict__ waf,
    const short* __restrict__ wcf, const float* __restrict__ ob,
    const float* __restrict__ mb, float* __restrict__ out)
{
    __shared__ float om[4 * 27 * 16];                //  6912 B

    int tid = threadIdx.x;
    int gid = blockIdx.x;
    // XCD-bijective swizzle: 1024 blocks = 8 XCDs x 128 contiguous
    int sid = (gid & 7) * 128 + (gid >> 3);
    int b = sid >> 8;
    int r = sid & 255;
    int h = r >> 1;
    int p0 = (r & 1) << 6;

    int wv = tid >> 6;
    int lane = tid & 63;
    int g = lane >> 4;
    int pl = lane & 15;
    int goff = g * 8;
    int xw = p0 + wv * 16 + pl;

    const short* xhb = xh + ((size_t)b << 20);
    float* omw = &om[wv * 27 * 16];

    // ---------------- phase 1: offset/mask conv (pipelined) ----------------
    floatx4 accC0 = {0.f, 0.f, 0.f, 0.f};
    floatx4 accC1 = {0.f, 0.f, 0.f, 0.f};

#define CADDR(K, P, V) do {                                                  \
    int ky = (K) / 3, kx = (K) - ky * 3;                                     \
    int yy = h + ky - 1, xx = xw + kx - 1;                                   \
    V = (yy >= 0) & (yy < HH) & (xx >= 0) & (xx < WW);                       \
    int yc = min(max(yy, 0), HH - 1), xc = min(max(xx, 0), WW - 1);          \
    P = ((yc * WW + xc) << 6) + goff;                                        \
} while (0)

#define CONVTAP(K, S0, S1, V) do {                                           \
    const short* wp = wcf + ((K) << 11) + lane * 8;                          \
    short8 w00 = *(const short8*)(wp + (0 << 9));                            \
    short8 w01 = *(const short8*)(wp + (1 << 9));                            \
    short8 w10 = *(const short8*)(wp + (2 << 9));                            \
    short8 w11 = *(const short8*)(wp + (3 << 9));                            \
    short8 z = {0, 0, 0, 0, 0, 0, 0, 0};                                     \
    short8 a0 = S0, a1 = S1;                                                 \
    if (!(V)) { a0 = z; a1 = z; }                                            \
    accC0 = __builtin_amdgcn_mfma_f32_16x16x32_bf16(w00, a0, accC0, 0, 0, 0);\
    accC1 = __builtin_amdgcn_mfma_f32_16x16x32_bf16(w01, a0, accC1, 0, 0, 0);\
    accC0 = __builtin_amdgcn_mfma_f32_16x16x32_bf16(w10, a1, accC0, 0, 0, 0);\
    accC1 = __builtin_amdgcn_mfma_f32_16x16x32_bf16(w11, a1, accC1, 0, 0, 0);\
} while (0)

    {
        bool vA, vB;
        int pa, pb;
        short8 A0, A1, B0, B1;
        CADDR(0, pa, vA);
        A0 = *(const short8*)(xhb + pa);
        A1 = *(const short8*)(xhb + pa + 32);
#pragma unroll 1
        for (int kp = 0; kp < 4; ++kp) {
            int k = kp * 2;
            CADDR(k + 1, pb, vB);
            B0 = *(const short8*)(xhb + pb);
            B1 = *(const short8*)(xhb + pb + 32);
            CONVTAP(k, A0, A1, vA);
            CADDR(k + 2, pa, vA);
            A0 = *(const short8*)(xhb + pa);
            A1 = *(const short8*)(xhb + pa + 32);
            CONVTAP(k + 1, B0, B1, vB);
        }
        CONVTAP(8, A0, A1, vA);
    }

    // om epilogue (wave-local LDS, no barrier needed)
#pragma unroll
    for (int j = 0; j < 4; ++j) {
        int o = g * 4 + j;
        omw[o * 16 + pl] = accC0[j] + ob[o];
        int o2 = 16 + g * 4 + j;
        float v = accC1[j];
        if (o2 < 18) omw[o2 * 16 + pl] = v + ob[o2];
        else if (o2 < 27)
            omw[o2 * 16 + pl] = 1.0f / (1.0f + expf(-(v + mb[o2 - 18])));
    }
    __builtin_amdgcn_s_waitcnt(0);   // ensure om LDS writes land before reads

    // ---------------- phase 2: deformable sampling + GEMM ----------------
    floatx4 acc0 = {0.f, 0.f, 0.f, 0.f}, acc1 = {0.f, 0.f, 0.f, 0.f};
    floatx4 acc2 = {0.f, 0.f, 0.f, 0.f}, acc3 = {0.f, 0.f, 0.f, 0.f};

#define MKTAP(K, I00, I01, I10, I11, U00, U01, U10, U11) do {                \
    int ky = (K) / 3, kx = (K) - ky * 3;                                     \
    float oy = omw[(2 * (K)) * 16 + pl];                                     \
    float ox = omw[(2 * (K) + 1) * 16 + pl];                                 \
    float mk = omw[(18 + (K)) * 16 + pl];                                    \
    float py = oy + (float)(h + ky - 1);                                     \
    float qx = ox + (float)(xw + kx - 1);                                    \
    float y0f = floorf(py), x0f = floorf(qx);                                \
    float dyy = py - y0f, dxx = qx - x0f;                                    \
    int y0 = (int)y0f, x0 = (int)x0f;                                        \
    int y1 = y0 + 1, x1 = x0 + 1;                                            \
    bool vy0 = (y0 >= 0) & (y0 < HH), vy1 = (y1 >= 0) & (y1 < HH);           \
    bool vx0 = (x0 >= 0) & (x0 < WW), vx1 = (x1 >= 0) & (x1 < WW);           \
    U00 = (vy0 & vx0) ? (1.f - dyy) * (1.f - dxx) * mk : 0.f;                \
    U01 = (vy0 & vx1) ? (1.f - dyy) * dxx * mk : 0.f;                        \
    U10 = (vy1 & vx0) ? dyy * (1.f - dxx) * mk : 0.f;                        \
    U11 = (vy1 & vx1) ? dyy * dxx * mk : 0.f;                                \
    int yc0 = min(max(y0, 0), HH - 1), yc1 = min(max(y1, 0), HH - 1);        \
    int xc0 = min(max(x0, 0), WW - 1), xc1 = min(max(x1, 0), WW - 1);        \
    I00 = ((yc0 * WW + xc0) << 6) + goff;                                    \
    I01 = ((yc0 * WW + xc1) << 6) + goff;                                    \
    I10 = ((yc1 * WW + xc0) << 6) + goff;                                    \
    I11 = ((yc1 * WW + xc1) << 6) + goff;                                    \
} while (0)

#define ISSUE8(I00, I01, I10, I11, C00, C01, C10, C11, D00, D01, D10, D11) do { \
    C00 = *(const short8*)(xhb + I00); C01 = *(const short8*)(xhb + I01);    \
    C10 = *(const short8*)(xhb + I10); C11 = *(const short8*)(xhb + I11);    \
    D00 = *(const short8*)(xhb + I00 + 32); D01 = *(const short8*)(xhb + I01 + 32); \
    D10 = *(const short8*)(xhb + I10 + 32); D11 = *(const short8*)(xhb + I11 + 32); \
} while (0)

#define BLEND(T, R0, R1, R2, R3, U00, U01, U10, U11) do {                    \
    _Pragma("unroll") for (int jj = 0; jj < 8; ++jj) {                       \
        float s = U00 * bf2f(R0[jj]) + U01 * bf2f(R1[jj])                    \
                + U10 * bf2f(R2[jj]) + U11 * bf2f(R3[jj]);                   \
        T[jj] = f2bf(s);                                                     \
    }                                                                        \
} while (0)

#define TAPMFMA(K, C00, C01, C10, C11, D00, D01, D10, D11, U00, U01, U10, U11) do { \
    const short* wk = waf + ((K) << 12) + lane * 8;                          \
    short8 q0 = *(const short8*)(wk + (0 << 9));                             \
    short8 q1 = *(const short8*)(wk + (1 << 9));                             \
    short8 q2 = *(const short8*)(wk + (2 << 9));                             \
    short8 q3 = *(const short8*)(wk + (3 << 9));                             \
    short8 bf;                                                               \
    BLEND(bf, C00, C01, C10, C11, U00, U01, U10, U11);                       \
    acc0 = __builtin_amdgcn_mfma_f32_16x16x32_bf16(q0, bf, acc0, 0, 0, 0);   \
    acc1 = __builtin_amdgcn_mfma_f32_16x16x32_bf16(q1, bf, acc1, 0, 0, 0);   \
    acc2 = __builtin_amdgcn_mfma_f32_16x16x32_bf16(q2, bf, acc2, 0, 0, 0);   \
    acc3 = __builtin_amdgcn_mfma_f32_16x16x32_bf16(q3, bf, acc3, 0, 0, 0);   \
    q0 = *(const short8*)(wk + (4 << 9));                                    \
    q1 = *(const short8*)(wk + (5 << 9));                                    \
    q2 = *(const short8*)(wk + (6 << 9));                                    \
    q3 = *(const short8*)(wk + (7 << 9));                                    \
    BLEND(bf, D00, D01, D10, D11, U00, U01, U10, U11);                       \
    acc0 = __builtin_amdgcn_mfma_f32_16x16x32_bf16(q0, bf, acc0, 0, 0, 0);   \
    acc1 = __builtin_amdgcn_mfma_f32_16x16x32_bf16(q1, bf, acc1, 0, 0, 0);   \
    acc2 = __builtin_amdgcn_mfma_f32_16x16x32_bf16(q2, bf, acc2, 0, 0, 0);   \
    acc3 = __builtin_amdgcn_mfma_f32_16x16x32_bf16(q3, bf, acc3, 0, 0, 0);   \
} while (0)

    {
        int iA00, iA01, iA10, iA11, iB00, iB01, iB10, iB11;
        float uA00, uA01, uA10, uA11, uB00, uB01, uB10, uB11;
        short8 cA00, cA01, cA10, cA11, dA00, dA01, dA10, dA11;
        short8 cB00, cB01, cB10, cB11, dB00, dB01, dB10, dB11;

        MKTAP(0, iA00, iA01, iA10, iA11, uA00, uA01, uA10, uA11);
        ISSUE8(iA00, iA01, iA10, iA11, cA00, cA01, cA10, cA11, dA00, dA01, dA10, dA11);
#pragma unroll 1
        for (int kp = 0; kp < 4; ++kp) {
            int k = kp * 2;
            MKTAP(k + 1, iB00, iB01, iB10, iB11, uB00, uB01, uB10, uB11);
            ISSUE8(iB00, iB01, iB10, iB11, cB00, cB01, cB10, cB11, dB00, dB01, dB10, dB11);
            TAPMFMA(k, cA00, cA01, cA10, cA11, dA00, dA01, dA10, dA11,
                    uA00, uA01, uA10, uA11);
            MKTAP(k + 2, iA00, iA01, iA10, iA11, uA00, uA01, uA10, uA11);
            ISSUE8(iA00, iA01, iA10, iA11, cA00, cA01, cA10, cA11, dA00, dA01, dA10, dA11);
            TAPMFMA(k + 1, cB00, cB01, cB10, cB11, dB00, dB01, dB10, dB11,
                    uB00, uB01, uB10, uB11);
        }
        TAPMFMA(8, cA00, cA01, cA10, cA11, dA00, dA01, dA10, dA11,
                uA00, uA01, uA10, uA11);
    }

    // epilogue: D col = pl, row o = m*16 + g*4 + j
    float* outp = out + (size_t)b * OO * HWsz + h * WW + p0 + wv * 16 + pl;
#pragma unroll
    for (int j = 0; j < 4; ++j) outp[(size_t)(g * 4 + j) * HWsz] = acc0[j];
#pragma unroll
    for (int j = 0; j < 4; ++j) outp[(size_t)(16 + g * 4 + j) * HWsz] = acc1[j];
#pragma unroll
    for (int j = 0; j < 4; ++j) outp[(size_t)(32 + g * 4 + j) * HWsz] = acc2[j];
#pragma unroll
    for (int j = 0; j < 4; ++j) outp[(size_t)(48 + g * 4 + j) * HWsz] = acc3[j];
}

extern "C" void kernel_launch(void* const* d_in, const int* in_sizes, int n_in,
                              void* d_out, int out_size, void* d_ws, size_t ws_size,
                              hipStream_t stream)
{
    const float* x   = (const float*)d_in[0];
    const float* ow  = (const float*)d_in[1];
    const float* ob  = (const float*)d_in[2];
    const float* mw  = (const float*)d_in[3];
    const float* mb  = (const float*)d_in[4];
    const float* wgt = (const float*)d_in[5];
    float* out = (float*)d_out;

    // ws: xh (4*16384*64 bf16 = 8.39MB) | waf (36864 bf16) | wcf (18432 bf16)
    short* xh  = (short*)d_ws;
    short* waf = xh + (size_t)BB * HWsz * 64;
    short* wcf = waf + 36864;

    pre_kernel<<<dim3(512 + 216), dim3(256), 0, stream>>>(
        x, wgt, ow, mw, xh, waf, wcf);
    fused_kernel<<<dim3(1024), dim3(256), 0, stream>>>(
        xh, waf, wcf, ob, mb, out);
}